// Round 15
// baseline (864.604 us; speedup 1.0000x reference)
//
#include <hip/hip_runtime.h>

typedef unsigned int uint;
typedef unsigned short ushort;

#define BN_EPS 1e-5f

using bf16x8 = __attribute__((ext_vector_type(8))) short;
using f32x16 = __attribute__((ext_vector_type(16))) float;

union FragU { uint w[4]; bf16x8 v; };

__device__ __forceinline__ uint pk2(float lo, float hi) {
    uint r;
    asm("v_cvt_pk_bf16_f32 %0, %1, %2" : "=v"(r) : "v"(lo), "v"(hi));
    return r;
}
__device__ __forceinline__ float bfu_lo(uint u) { return __uint_as_float(u << 16); }
__device__ __forceinline__ float bfu_hi(uint u) { return __uint_as_float(u & 0xffff0000u); }

__device__ __forceinline__ float upk(const uint* p, int idx) {
    uint u = p[idx >> 1];
    return (idx & 1) ? bfu_hi(u) : bfu_lo(u);
}
__device__ __forceinline__ float upq(const uint2* gq, int r) {
    int g = r >> 2, j = r & 3;
    uint u = (j < 2) ? gq[g].x : gq[g].y;
    return (j & 1) ? bfu_hi(u) : bfu_lo(u);
}

// Self-calibration: true D-reg -> row mapping of mfma_f32_32x32x16_bf16.
__device__ __forceinline__ void get_rowmap(int col, int* rowv) {
    FragU pa, pb;
    float c = (float)col;
    #pragma unroll
    for (int j = 0; j < 4; j++) { pa.w[j] = pk2(c, c); pb.w[j] = pk2(1.f, 1.f); }
    f32x16 d;
    #pragma unroll
    for (int r = 0; r < 16; r++) d[r] = 0.f;
    d = __builtin_amdgcn_mfma_f32_32x32x16_bf16(pa.v, pb.v, d, 0, 0, 0);
    #pragma unroll
    for (int r = 0; r < 16; r++) {
        int m = (int)(d[r] * 0.0625f + 0.5f);
        rowv[r] = (m < 0) ? 0 : (m > 31 ? 31 : m);
    }
}

template<bool SORTED>
__device__ __forceinline__ void edge_sd(int e, const int* __restrict__ ei,
                                        const int* __restrict__ srcs,
                                        const int* __restrict__ dsts,
                                        int nE, int& src, int& dst) {
    if (SORTED) { src = srcs[e]; dst = dsts[e]; }
    else if (e < nE) { src = ei[e]; dst = ei[nE + e]; }
    else { src = e - nE; dst = src; }
}

// ---------- node linears -> asx: interleaved [aS(16u) | xv(16u)] 128B rows; aDb separate ----------
__global__ __launch_bounds__(256) void k_node_lin(
    const float* __restrict__ x,
    const float* __restrict__ w_src, const float* __restrict__ w_dst,
    const float* __restrict__ w_lin,
    uint* __restrict__ asx, uint* __restrict__ aDb,
    int nNodes)
{
    int n = blockIdx.x * 256 + threadIdx.x;
    if (n >= nNodes) return;
    float xr[64];
    const float4* xp = (const float4*)(x + (size_t)n * 64);
    #pragma unroll
    for (int i = 0; i < 16; i++) {
        float4 v = xp[i];
        xr[4*i] = v.x; xr[4*i+1] = v.y; xr[4*i+2] = v.z; xr[4*i+3] = v.w;
    }
    const float* ws[3] = { w_src, w_lin, w_dst };
    uint* outs[3] = { asx + (size_t)n*32, asx + (size_t)n*32 + 16, aDb + (size_t)n*16 };
    #pragma unroll
    for (int m = 0; m < 3; m++) {
        const float* w = ws[m];
        float acc[32];
        #pragma unroll
        for (int o = 0; o < 32; o++) acc[o] = 0.f;
        #pragma unroll
        for (int k = 0; k < 64; k++) {
            float xk = xr[k];
            #pragma unroll
            for (int o = 0; o < 32; o++) acc[o] = fmaf(xk, w[k*32+o], acc[o]);
        }
        uint4* op = (uint4*)outs[m];
        #pragma unroll
        for (int q = 0; q < 4; q++) {
            uint4 v;
            v.x = pk2(acc[8*q+0], acc[8*q+1]);
            v.y = pk2(acc[8*q+2], acc[8*q+3]);
            v.z = pk2(acc[8*q+4], acc[8*q+5]);
            v.w = pk2(acc[8*q+6], acc[8*q+7]);
            op[q] = v;
        }
    }
}

// ---------- pos -> float4 ----------
__global__ __launch_bounds__(256) void k_pos4(
    const float* __restrict__ pos, float4* __restrict__ pos4, int n)
{
    int i = blockIdx.x * 256 + threadIdx.x;
    if (i < n) pos4[i] = make_float4(pos[i*3], pos[i*3+1], pos[i*3+2], 0.f);
}

// ---------- sort-by-dst ----------
__global__ __launch_bounds__(256) void k_hist(
    const int* __restrict__ ei, int* __restrict__ cnt, int nE, int eTot)
{
    int e = blockIdx.x * 256 + threadIdx.x;
    if (e >= eTot) return;
    int dst = (e < nE) ? ei[nE + e] : (e - nE);
    atomicAdd(&cnt[dst], 1);
}

#define SCH 1024
__global__ __launch_bounds__(256) void k_scan1(
    const int* __restrict__ cnt, int* __restrict__ cur,
    int* __restrict__ blkS, int n)
{
    __shared__ int ls[256];
    int t = threadIdx.x;
    int base = blockIdx.x * SCH + t * 4;
    int v0 = (base+0 < n) ? cnt[base+0] : 0;
    int v1 = (base+1 < n) ? cnt[base+1] : 0;
    int v2 = (base+2 < n) ? cnt[base+2] : 0;
    int v3 = (base+3 < n) ? cnt[base+3] : 0;
    int tsum = v0 + v1 + v2 + v3;
    ls[t] = tsum;
    __syncthreads();
    for (int o = 1; o < 256; o <<= 1) {
        int x = (t >= o) ? ls[t-o] : 0;
        __syncthreads();
        ls[t] += x;
        __syncthreads();
    }
    if (t == 255) blkS[blockIdx.x] = ls[255];
    int run = ls[t] - tsum;
    if (base+0 < n) cur[base+0] = run; run += v0;
    if (base+1 < n) cur[base+1] = run; run += v1;
    if (base+2 < n) cur[base+2] = run; run += v2;
    if (base+3 < n) cur[base+3] = run;
}

__global__ void k_scan2(const int* __restrict__ blkS, int* __restrict__ blkOff, int nb)
{
    __shared__ int ls[256];
    int t = threadIdx.x;
    int v = (t < nb) ? blkS[t] : 0;
    ls[t] = v;
    __syncthreads();
    for (int o = 1; o < 256; o <<= 1) {
        int x = (t >= o) ? ls[t-o] : 0;
        __syncthreads();
        ls[t] += x;
        __syncthreads();
    }
    if (t < nb) blkOff[t] = ls[t] - v;
}

__global__ __launch_bounds__(256) void k_scan3(
    int* __restrict__ cur, const int* __restrict__ blkOff, int n)
{
    int off = blkOff[blockIdx.x];
    int base = blockIdx.x * SCH + threadIdx.x * 4;
    #pragma unroll
    for (int j = 0; j < 4; j++) {
        int i = base + j;
        if (i < n) cur[i] += off;
    }
}

__global__ __launch_bounds__(256) void k_rank(
    const int* __restrict__ ei, int* __restrict__ cur,
    int* __restrict__ srcs, int* __restrict__ dsts, int nE, int eTot)
{
    int e = blockIdx.x * 256 + threadIdx.x;
    if (e >= eTot) return;
    int src, dst;
    if (e < nE) { src = ei[e]; dst = ei[nE + e]; }
    else        { src = e - nE; dst = src; }
    int slot = atomicAdd(&cur[dst], 1);
    srcs[slot] = src; dsts[slot] = dst;
}

// ---------- pass 0: 9 moments of d (block partials) ----------
__global__ __launch_bounds__(256) void k_pos_mom(
    const int* __restrict__ ei, const float4* __restrict__ pos4,
    float* __restrict__ partM, int nE)
{
    float m[9];
    #pragma unroll
    for (int c = 0; c < 9; c++) m[c] = 0.f;
    int stride = gridDim.x * blockDim.x;
    for (int e = blockIdx.x * blockDim.x + threadIdx.x; e < nE; e += stride) {
        int src = ei[e], dst = ei[nE + e];
        float4 pd = pos4[dst], ps = pos4[src];
        float d0 = pd.x - ps.x, d1 = pd.y - ps.y, d2 = pd.z - ps.z;
        m[0] += d0; m[1] += d1; m[2] += d2;
        m[3] = fmaf(d0,d0,m[3]); m[4] = fmaf(d0,d1,m[4]); m[5] = fmaf(d0,d2,m[5]);
        m[6] = fmaf(d1,d1,m[6]); m[7] = fmaf(d1,d2,m[7]); m[8] = fmaf(d2,d2,m[8]);
    }
    __shared__ float red[4][9];
    int w = threadIdx.x >> 6;
    #pragma unroll
    for (int c = 0; c < 9; c++) {
        float t = m[c];
        for (int o = 32; o > 0; o >>= 1) t += __shfl_down(t, o, 64);
        if ((threadIdx.x & 63) == 0) red[w][c] = t;
    }
    __syncthreads();
    if (threadIdx.x < 9)
        partM[blockIdx.x * 9 + threadIdx.x] =
            red[0][threadIdx.x] + red[1][threadIdx.x] + red[2][threadIdx.x] + red[3][threadIdx.x];
}

__global__ void k_bn1_mom(const float* __restrict__ partM, int nBlk,
                          const float* __restrict__ pw1, const float* __restrict__ pb1,
                          const float* __restrict__ g, const float* __restrict__ beta,
                          float* __restrict__ bn, float invE)
{
    __shared__ float mom_s[9];
    int l = threadIdx.x;
    #pragma unroll
    for (int c = 0; c < 9; c++) {
        float s = 0.f;
        for (int i = l; i < nBlk; i += 64) s += partM[i*9 + c];
        for (int o = 32; o > 0; o >>= 1) s += __shfl_down(s, o, 64);
        if (l == 0) mom_s[c] = s;
    }
    __syncthreads();
    int c = l;
    if (c < 64) {
        float w0 = pw1[c], w1 = pw1[64+c], w2 = pw1[128+c], b = pb1[c];
        float S = fmaf(w0, mom_s[0], fmaf(w1, mom_s[1], w2 * mom_s[2]));
        float Q = w0*w0*mom_s[3] + 2.f*w0*w1*mom_s[4] + 2.f*w0*w2*mom_s[5]
                + w1*w1*mom_s[6] + 2.f*w1*w2*mom_s[7] + w2*w2*mom_s[8];
        float mu  = S * invE + b;
        float E2  = Q * invE + 2.f * b * (S * invE) + b * b;
        float var = fmaxf(E2 - mu * mu, 0.f);
        float sc  = rsqrtf(var + BN_EPS) * g[c];
        bn[c]      = sc;
        bn[64+c]   = beta[c] - mu * sc;
    }
}

__global__ __launch_bounds__(256) void k_red_stats(
    const float* __restrict__ partD, float* __restrict__ stats2, int nBlk)
{
    int c = blockIdx.x;  // 0..127
    float s = 0.f;
    for (int i = threadIdx.x; i < nBlk; i += 256) s += partD[(size_t)i*128 + c];
    for (int o = 32; o > 0; o >>= 1) s += __shfl_down(s, o, 64);
    __shared__ float red[4];
    if ((threadIdx.x & 63) == 0) red[threadIdx.x >> 6] = s;
    __syncthreads();
    if (threadIdx.x == 0) stats2[c] = red[0] + red[1] + red[2] + red[3];
}

__global__ void k_bn_fin(const float* __restrict__ stats,
                         const float* __restrict__ g, const float* __restrict__ beta,
                         const float* __restrict__ bias,
                         float* __restrict__ bn, float inv_ep)
{
    int c = threadIdx.x;
    if (c < 64) {
        float b   = bias ? bias[c] : 0.f;
        float m0  = stats[c] * inv_ep;
        float mu  = m0 + b;
        float eq  = stats[64+c] * inv_ep + 2.f*b*m0 + b*b;
        float var = fmaxf(eq - mu * mu, 0.f);
        float sc  = rsqrtf(var + BN_EPS) * g[c];
        bn[c]      = sc;
        bn[64+c]   = beta[c] - mu * sc;
    }
}

__global__ void k_fold1(const float* __restrict__ pw1, const float* __restrict__ pb1,
                        const float* __restrict__ bn1,
                        float* __restrict__ pw1f, float* __restrict__ pb1f)
{
    int i = threadIdx.x;
    if (i < 192) pw1f[i] = pw1[i] * bn1[i & 63];
    if (i < 64)  pb1f[i] = pb1[i] * bn1[i] + bn1[64 + i];
}

__global__ void k_fold2(const float* __restrict__ aw1, const float* __restrict__ ab1,
                        const float* __restrict__ bn2,
                        float* __restrict__ aw1f, float* __restrict__ ab1f)
{
    int i = blockIdx.x * 256 + threadIdx.x;
    if (i < 2048) aw1f[i] = aw1[i] * bn2[i & 63];
    if (i < 64)   ab1f[i] = ab1[i] * bn2[i] + bn2[64 + i];
}

// ---------- pass 1: delta + raw h2 stats (direct gathers, block partials) ----------
template<bool SORTED>
__global__ __launch_bounds__(256, 2) void k_delta_stats(
    const int* __restrict__ ei, const int* __restrict__ srcs, const int* __restrict__ dsts,
    const float4* __restrict__ pos4,
    const uint* __restrict__ asx, const uint* __restrict__ aDb,
    const float* __restrict__ pw1f, const float* __restrict__ pb1f,
    const float* __restrict__ pw2, const float* __restrict__ pb2,
    const float* __restrict__ aw1,
    float* __restrict__ partD, int nE, int eTot)
{
    const int lane = threadIdx.x & 63;
    const int col  = lane & 31;
    const int h    = lane >> 5;

    __shared__ float redS[4][64], redQ[4][64];
    {
        int w = threadIdx.x >> 6, c = threadIdx.x & 63;
        redS[w][c] = 0.f; redQ[w][c] = 0.f;
    }

    bool quadOK;
    int q2[4];
    FragU fw_pw2[4];
    FragU fw_aw1[2][2];
    uint pb2p[8];
    int rowv[16];
    {
        get_rowmap(col, rowv);
        quadOK = true;
        #pragma unroll
        for (int g = 0; g < 4; g++)
            quadOK = quadOK && (rowv[4*g+1] == rowv[4*g]+1)
                            && (rowv[4*g+2] == rowv[4*g]+2)
                            && (rowv[4*g+3] == rowv[4*g]+3);
        #pragma unroll
        for (int g = 0; g < 4; g++) q2[g] = rowv[4*g] >> 2;
        #pragma unroll
        for (int kt = 0; kt < 4; kt++)
            #pragma unroll
            for (int jw = 0; jw < 4; jw++) {
                int m = 2*jw;
                int c0 = 16*kt + 8*(m>>2) + 4*h + (m&3);
                fw_pw2[kt].w[jw] = pk2(pw2[c0*32 + col], pw2[(c0+1)*32 + col]);
            }
        #pragma unroll
        for (int mt = 0; mt < 2; mt++)
            #pragma unroll
            for (int kt = 0; kt < 2; kt++)
                #pragma unroll
                for (int jw = 0; jw < 4; jw++) {
                    int u0 = rowv[8*kt + 2*jw], u1 = rowv[8*kt + 2*jw + 1];
                    fw_aw1[mt][kt].w[jw] = pk2(aw1[u0*64 + 32*mt + col],
                                               aw1[u1*64 + 32*mt + col]);
                }
        #pragma unroll
        for (int g = 0; g < 8; g++)
            pb2p[g] = pk2(pb2[rowv[2*g]], pb2[rowv[2*g+1]]);
    }

    float sA[32], qA[32];
    #pragma unroll
    for (int i = 0; i < 32; i++) { sA[i] = 0.f; qA[i] = 0.f; }

    const int nT = (eTot + 31) >> 5;
    const int gw = (blockIdx.x << 2) + (threadIdx.x >> 6);
    const int nW = gridDim.x << 2;

    for (int t = gw; t < nT; t += nW) {
        int e = t*32 + col;
        bool valid = e < eTot;
        int ec = valid ? e : eTot - 1;
        int src, dst;
        edge_sd<SORTED>(ec, ei, srcs, dsts, nE, src, dst);
        float4 ps = pos4[src], pd = pos4[dst];
        float p0 = pd.x - ps.x, p1 = pd.y - ps.y, p2 = pd.z - ps.z;

        // direct gathers (issued early)
        uint2 gs2[4], gd2[4];
        float gSs[16], gDs[16];
        if (quadOK) {
            const uint* rs = asx + (size_t)src*32;
            const uint* rd = aDb + (size_t)dst*16;
            #pragma unroll
            for (int g = 0; g < 4; g++) gs2[g] = *(const uint2*)(rs + 2*q2[g]);
            #pragma unroll
            for (int g = 0; g < 4; g++) gd2[g] = *(const uint2*)(rd + 2*q2[g]);
        } else {
            const ushort* rs = (const ushort*)(asx + (size_t)src*32);
            const ushort* rd = (const ushort*)(aDb + (size_t)dst*16);
            #pragma unroll
            for (int r = 0; r < 16; r++) {
                gSs[r] = __uint_as_float(((uint)rs[rowv[r]]) << 16);
                gDs[r] = __uint_as_float(((uint)rd[rowv[r]]) << 16);
            }
        }

        FragU ft[4];
        #pragma unroll
        for (int kt = 0; kt < 4; kt++)
            #pragma unroll
            for (int mm = 0; mm < 2; mm++) {
                int cb = 16*kt + 8*mm + 4*h;
                float4 w0 = *(const float4*)(pw1f +       cb);
                float4 w1 = *(const float4*)(pw1f + 64  + cb);
                float4 w2 = *(const float4*)(pw1f + 128 + cb);
                float4 bb = *(const float4*)(pb1f + cb);
                float t0 = fmaxf(fmaf(p0,w0.x, fmaf(p1,w1.x, fmaf(p2,w2.x, bb.x))), 0.f);
                float t1 = fmaxf(fmaf(p0,w0.y, fmaf(p1,w1.y, fmaf(p2,w2.y, bb.y))), 0.f);
                float t2 = fmaxf(fmaf(p0,w0.z, fmaf(p1,w1.z, fmaf(p2,w2.z, bb.z))), 0.f);
                float t3 = fmaxf(fmaf(p0,w0.w, fmaf(p1,w1.w, fmaf(p2,w2.w, bb.w))), 0.f);
                ft[kt].w[2*mm+0] = pk2(t0, t1);
                ft[kt].w[2*mm+1] = pk2(t2, t3);
            }
        f32x16 adl;
        #pragma unroll
        for (int r = 0; r < 16; r++) adl[r] = upk(pb2p, r);
        #pragma unroll
        for (int kt = 0; kt < 4; kt++)
            adl = __builtin_amdgcn_mfma_f32_32x32x16_bf16(fw_pw2[kt].v, ft[kt].v, adl, 0, 0, 0);

        FragU fu[2];
        if (quadOK) {
            #pragma unroll
            for (int kt = 0; kt < 2; kt++)
                #pragma unroll
                for (int jw = 0; jw < 4; jw++) {
                    int r0 = 8*kt + 2*jw;
                    fu[kt].w[jw] = pk2(adl[r0]   + upq(gd2, r0)   - upq(gs2, r0),
                                       adl[r0+1] + upq(gd2, r0+1) - upq(gs2, r0+1));
                }
        } else {
            #pragma unroll
            for (int kt = 0; kt < 2; kt++)
                #pragma unroll
                for (int jw = 0; jw < 4; jw++) {
                    int r0 = 8*kt + 2*jw;
                    fu[kt].w[jw] = pk2(adl[r0]   + gDs[r0]   - gSs[r0],
                                       adl[r0+1] + gDs[r0+1] - gSs[r0+1]);
                }
        }

        f32x16 ah0, ah1;
        #pragma unroll
        for (int r = 0; r < 16; r++) { ah0[r] = 0.f; ah1[r] = 0.f; }
        #pragma unroll
        for (int kt = 0; kt < 2; kt++) {
            ah0 = __builtin_amdgcn_mfma_f32_32x32x16_bf16(fw_aw1[0][kt].v, fu[kt].v, ah0, 0, 0, 0);
            ah1 = __builtin_amdgcn_mfma_f32_32x32x16_bf16(fw_aw1[1][kt].v, fu[kt].v, ah1, 0, 0, 0);
        }
        if (valid) {
            #pragma unroll
            for (int r = 0; r < 16; r++) {
                sA[r]    += ah0[r];
                qA[r]     = fmaf(ah0[r], ah0[r], qA[r]);
                sA[16+r] += ah1[r];
                qA[16+r]  = fmaf(ah1[r], ah1[r], qA[16+r]);
            }
        }
    }

    __syncthreads();
    {
        int w = threadIdx.x >> 6;
        #pragma unroll
        for (int idx = 0; idx < 32; idx++) {
            float vs = sA[idx], vq = qA[idx];
            for (int off = 16; off > 0; off >>= 1) {
                vs += __shfl_xor(vs, off, 64);
                vq += __shfl_xor(vq, off, 64);
            }
            if ((threadIdx.x & 31) == 0) {
                int mt = idx >> 4, r = idx & 15;
                int c = 32*mt + rowv[r];
                redS[w][c] = vs;
                redQ[w][c] = vq;
            }
        }
    }
    __syncthreads();
    if (threadIdx.x < 64) {
        int c = threadIdx.x;
        float S = redS[0][c] + redS[1][c] + redS[2][c] + redS[3][c];
        float Q = redQ[0][c] + redQ[1][c] + redQ[2][c] + redQ[3][c];
        partD[(size_t)blockIdx.x*128 + c]      = S;
        partD[(size_t)blockIdx.x*128 + 64 + c] = Q;
    }
}

// ---------- pass 2: full pipeline + exp + segmented-reduced atomics (inline LDS staging, r11-style) ----------
template<bool SORTED>
__global__ __launch_bounds__(256, 2) void k_att_agg(
    const int* __restrict__ ei, const int* __restrict__ srcs, const int* __restrict__ dsts,
    const float4* __restrict__ pos4,
    const uint* __restrict__ asx, const uint* __restrict__ aDb,
    const float* __restrict__ pw1f, const float* __restrict__ pb1f,
    const float* __restrict__ pw2, const float* __restrict__ pb2,
    const float* __restrict__ aw1f, const float* __restrict__ ab1f,
    const float* __restrict__ aw2, const float* __restrict__ ab2,
    float* __restrict__ denom, float* __restrict__ outp,
    int nE, int eTot)
{
    const int lane = threadIdx.x & 63;
    const int col  = lane & 31;
    const int h    = lane >> 5;
    const int wid  = threadIdx.x >> 6;

    __shared__ uint sbuf[4][1024];   // per-wave 32 rows x 32 uints (swizzled)

    bool quadOK;
    int q2[4];
    int rowv[16];
    FragU fw_pw2[4], fw_aw2[4];
    FragU fw_aw1[2][2];
    uint pb2p[8], ab2p[8], ab1p[16];
    {
        get_rowmap(col, rowv);
        quadOK = true;
        #pragma unroll
        for (int g = 0; g < 4; g++)
            quadOK = quadOK && (rowv[4*g+1] == rowv[4*g]+1)
                            && (rowv[4*g+2] == rowv[4*g]+2)
                            && (rowv[4*g+3] == rowv[4*g]+3);
        #pragma unroll
        for (int g = 0; g < 4; g++) q2[g] = rowv[4*g] >> 2;
        #pragma unroll
        for (int kt = 0; kt < 4; kt++)
            #pragma unroll
            for (int jw = 0; jw < 4; jw++) {
                int m = 2*jw;
                int c0 = 16*kt + 8*(m>>2) + 4*h + (m&3);
                fw_pw2[kt].w[jw] = pk2(pw2[c0*32 + col], pw2[(c0+1)*32 + col]);
                int o0 = 32*(kt>>1) + rowv[8*(kt&1) + m];
                int o1 = 32*(kt>>1) + rowv[8*(kt&1) + m + 1];
                fw_aw2[kt].w[jw] = pk2(aw2[o0*32 + col], aw2[o1*32 + col]);
            }
        #pragma unroll
        for (int mt = 0; mt < 2; mt++)
            #pragma unroll
            for (int kt = 0; kt < 2; kt++)
                #pragma unroll
                for (int jw = 0; jw < 4; jw++) {
                    int u0 = rowv[8*kt + 2*jw], u1 = rowv[8*kt + 2*jw + 1];
                    fw_aw1[mt][kt].w[jw] = pk2(aw1f[u0*64 + 32*mt + col],
                                               aw1f[u1*64 + 32*mt + col]);
                }
        #pragma unroll
        for (int g = 0; g < 8; g++) {
            pb2p[g] = pk2(pb2[rowv[2*g]], pb2[rowv[2*g+1]]);
            ab2p[g] = pk2(ab2[rowv[2*g]], ab2[rowv[2*g+1]]);
            ab1p[g]     = pk2(ab1f[rowv[2*g]],      ab1f[rowv[2*g+1]]);
            ab1p[8 + g] = pk2(ab1f[32 + rowv[2*g]], ab1f[32 + rowv[2*g+1]]);
        }
    }

    const int nT = (eTot + 31) >> 5;
    const int gw = (blockIdx.x << 2) + (threadIdx.x >> 6);
    const int nW = gridDim.x << 2;

    if (quadOK) {
        for (int t = gw; t < nT; t += nW) {
            int e = t*32 + col;
            bool valid = e < eTot;
            int ec = valid ? e : eTot - 1;
            int src, dst;
            edge_sd<SORTED>(ec, ei, srcs, dsts, nE, src, dst);
            // cooperative stage of the 32 asx rows (coalesced: 8 lanes per 128B row)
            #pragma unroll
            for (int it = 0; it < 4; it++) {
                int j  = it*8 + (lane >> 3);
                int sj = __shfl(src, j, 64);
                int w  = lane & 7;
                uint4 v = *(const uint4*)(asx + (size_t)sj*32 + w*4);
                *(uint4*)&sbuf[wid][j*32 + ((w ^ (j & 7)) << 2)] = v;
            }
            float4 ps = pos4[src], pd = pos4[dst];
            uint2 gd2[4];
            {
                const uint* rd = aDb + (size_t)dst*16;
                #pragma unroll
                for (int g = 0; g < 4; g++) gd2[g] = *(const uint2*)(rd + 2*q2[g]);
            }
            float p0 = pd.x - ps.x, p1 = pd.y - ps.y, p2 = pd.z - ps.z;

            FragU ft[4];
            #pragma unroll
            for (int kt = 0; kt < 4; kt++)
                #pragma unroll
                for (int mm = 0; mm < 2; mm++) {
                    int cb = 16*kt + 8*mm + 4*h;
                    float4 w0 = *(const float4*)(pw1f +       cb);
                    float4 w1 = *(const float4*)(pw1f + 64  + cb);
                    float4 w2 = *(const float4*)(pw1f + 128 + cb);
                    float4 bb = *(const float4*)(pb1f + cb);
                    float t0 = fmaxf(fmaf(p0,w0.x, fmaf(p1,w1.x, fmaf(p2,w2.x, bb.x))), 0.f);
                    float t1 = fmaxf(fmaf(p0,w0.y, fmaf(p1,w1.y, fmaf(p2,w2.y, bb.y))), 0.f);
                    float t2 = fmaxf(fmaf(p0,w0.z, fmaf(p1,w1.z, fmaf(p2,w2.z, bb.z))), 0.f);
                    float t3 = fmaxf(fmaf(p0,w0.w, fmaf(p1,w1.w, fmaf(p2,w2.w, bb.w))), 0.f);
                    ft[kt].w[2*mm+0] = pk2(t0, t1);
                    ft[kt].w[2*mm+1] = pk2(t2, t3);
                }
            f32x16 adl;
            #pragma unroll
            for (int r = 0; r < 16; r++) adl[r] = upk(pb2p, r);
            #pragma unroll
            for (int kt = 0; kt < 4; kt++)
                adl = __builtin_amdgcn_mfma_f32_32x32x16_bf16(fw_pw2[kt].v, ft[kt].v, adl, 0, 0, 0);

            // read staged fragments (aS half + xv half)
            uint2 gs2[4], gx2[4];
            #pragma unroll
            for (int g = 0; g < 4; g++) {
                int wq = q2[g] >> 1, hf = (q2[g] & 1) << 1;
                gs2[g] = *(const uint2*)&sbuf[wid][col*32 + ((wq ^ (col & 7)) << 2) + hf];
                gx2[g] = *(const uint2*)&sbuf[wid][col*32 + (((4 + wq) ^ (col & 7)) << 2) + hf];
            }

            FragU fu[2];
            #pragma unroll
            for (int kt = 0; kt < 2; kt++)
                #pragma unroll
                for (int jw = 0; jw < 4; jw++) {
                    int r0 = 8*kt + 2*jw;
                    fu[kt].w[jw] = pk2(adl[r0]   + upq(gd2, r0)   - upq(gs2, r0),
                                       adl[r0+1] + upq(gd2, r0+1) - upq(gs2, r0+1));
                }

            f32x16 ah0, ah1;
            #pragma unroll
            for (int r = 0; r < 16; r++) { ah0[r] = upk(ab1p, r); ah1[r] = upk(ab1p, 16 + r); }
            #pragma unroll
            for (int kt = 0; kt < 2; kt++) {
                ah0 = __builtin_amdgcn_mfma_f32_32x32x16_bf16(fw_aw1[0][kt].v, fu[kt].v, ah0, 0, 0, 0);
                ah1 = __builtin_amdgcn_mfma_f32_32x32x16_bf16(fw_aw1[1][kt].v, fu[kt].v, ah1, 0, 0, 0);
            }
            FragU fh[4];
            #pragma unroll
            for (int q = 0; q < 4; q++)
                #pragma unroll
                for (int jw = 0; jw < 4; jw++) {
                    int r0 = 8*(q&1) + 2*jw;
                    float x0 = (q < 2) ? ah0[r0]   : ah1[r0];
                    float x1 = (q < 2) ? ah0[r0+1] : ah1[r0+1];
                    fh[q].w[jw] = pk2(fmaxf(x0, 0.f), fmaxf(x1, 0.f));
                }
            f32x16 aa;
            #pragma unroll
            for (int r = 0; r < 16; r++) aa[r] = upk(ab2p, r);
            aa = __builtin_amdgcn_mfma_f32_32x32x16_bf16(fw_aw2[0].v, fh[0].v, aa, 0, 0, 0);
            aa = __builtin_amdgcn_mfma_f32_32x32x16_bf16(fw_aw2[1].v, fh[1].v, aa, 0, 0, 0);
            aa = __builtin_amdgcn_mfma_f32_32x32x16_bf16(fw_aw2[2].v, fh[2].v, aa, 0, 0, 0);
            aa = __builtin_amdgcn_mfma_f32_32x32x16_bf16(fw_aw2[3].v, fh[3].v, aa, 0, 0, 0);

            if (SORTED) {
                int lw = lane & 31;
                int dprev = __shfl_up(dst, 1, 32);
                bool isHead = (lw == 0) || (dprev != dst);
                bool eq1  = (__shfl_down(dst, 1, 32)  == dst) && (lw + 1  < 32);
                bool eq2  = (__shfl_down(dst, 2, 32)  == dst) && (lw + 2  < 32);
                bool eq4  = (__shfl_down(dst, 4, 32)  == dst) && (lw + 4  < 32);
                bool eq8  = (__shfl_down(dst, 8, 32)  == dst) && (lw + 8  < 32);
                bool eq16 = (__shfl_down(dst, 16, 32) == dst) && (lw + 16 < 32);
                float* drow = denom + (size_t)dst * 32;
                float* orow = outp  + (size_t)dst * 32;
                #pragma unroll
                for (int r = 0; r < 16; r++) {
                    float ea = __expf(fminf(aa[r], 35.f));
                    float ev = valid ? ea : 0.f;
                    float mv = valid ? ea * (upq(gx2, r) + adl[r]) : 0.f;
                    { float a = __shfl_down(ev,1,32),  b = __shfl_down(mv,1,32);  if (eq1)  { ev += a; mv += b; } }
                    { float a = __shfl_down(ev,2,32),  b = __shfl_down(mv,2,32);  if (eq2)  { ev += a; mv += b; } }
                    { float a = __shfl_down(ev,4,32),  b = __shfl_down(mv,4,32);  if (eq4)  { ev += a; mv += b; } }
                    { float a = __shfl_down(ev,8,32),  b = __shfl_down(mv,8,32);  if (eq8)  { ev += a; mv += b; } }
                    { float a = __shfl_down(ev,16,32), b = __shfl_down(mv,16,32); if (eq16) { ev += a; mv += b; } }
                    if (isHead) {
                        int o = 4*q2[r>>2] + (r&3);
                        unsafeAtomicAdd(drow + o, ev);
                        unsafeAtomicAdd(orow + o, mv);
                    }
                }
            } else if (valid) {
                float* drow = denom + (size_t)dst * 32;
                float* orow = outp  + (size_t)dst * 32;
                #pragma unroll
                for (int r = 0; r < 16; r++) {
                    int o = 4*q2[r>>2] + (r&3);
                    float ea = __expf(fminf(aa[r], 35.f));
                    unsafeAtomicAdd(drow + o, ea);
                    unsafeAtomicAdd(orow + o, ea * (upq(gx2, r) + adl[r]));
                }
            }
        }
    } else {
        // generic fallback: per-lane scalar gathers, no staging
        for (int t = gw; t < nT; t += nW) {
            int e = t*32 + col;
            bool valid = e < eTot;
            int ec = valid ? e : eTot - 1;
            int src, dst;
            edge_sd<SORTED>(ec, ei, srcs, dsts, nE, src, dst);
            float4 pd = pos4[dst], ps = pos4[src];
            float p0 = pd.x - ps.x, p1 = pd.y - ps.y, p2 = pd.z - ps.z;
            const ushort* rs = (const ushort*)(asx + (size_t)src*32);
            const ushort* rd = (const ushort*)(aDb + (size_t)dst*16);
            float gSs[16], gDs[16], xg[16];
            #pragma unroll
            for (int r = 0; r < 16; r++) {
                gSs[r] = __uint_as_float(((uint)rs[rowv[r]]) << 16);
                gDs[r] = __uint_as_float(((uint)rd[rowv[r]]) << 16);
                xg[r]  = __uint_as_float(((uint)rs[32 + rowv[r]]) << 16);
            }
            FragU ft[4];
            #pragma unroll
            for (int kt = 0; kt < 4; kt++)
                #pragma unroll
                for (int mm = 0; mm < 2; mm++) {
                    int cb = 16*kt + 8*mm + 4*h;
                    float4 w0 = *(const float4*)(pw1f +       cb);
                    float4 w1 = *(const float4*)(pw1f + 64  + cb);
                    float4 w2 = *(const float4*)(pw1f + 128 + cb);
                    float4 bb = *(const float4*)(pb1f + cb);
                    float t0 = fmaxf(fmaf(p0,w0.x, fmaf(p1,w1.x, fmaf(p2,w2.x, bb.x))), 0.f);
                    float t1 = fmaxf(fmaf(p0,w0.y, fmaf(p1,w1.y, fmaf(p2,w2.y, bb.y))), 0.f);
                    float t2 = fmaxf(fmaf(p0,w0.z, fmaf(p1,w1.z, fmaf(p2,w2.z, bb.z))), 0.f);
                    float t3 = fmaxf(fmaf(p0,w0.w, fmaf(p1,w1.w, fmaf(p2,w2.w, bb.w))), 0.f);
                    ft[kt].w[2*mm+0] = pk2(t0, t1);
                    ft[kt].w[2*mm+1] = pk2(t2, t3);
                }
            f32x16 adl;
            #pragma unroll
            for (int r = 0; r < 16; r++) adl[r] = upk(pb2p, r);
            #pragma unroll
            for (int kt = 0; kt < 4; kt++)
                adl = __builtin_amdgcn_mfma_f32_32x32x16_bf16(fw_pw2[kt].v, ft[kt].v, adl, 0, 0, 0);
            FragU fu[2];
            #pragma unroll
            for (int kt = 0; kt < 2; kt++)
                #pragma unroll
                for (int jw = 0; jw < 4; jw++) {
                    int r0 = 8*kt + 2*jw;
                    fu[kt].w[jw] = pk2(adl[r0]   + gDs[r0]   - gSs[r0],
                                       adl[r0+1] + gDs[r0+1] - gSs[r0+1]);
                }
            f32x16 ah0, ah1;
            #pragma unroll
            for (int r = 0; r < 16; r++) { ah0[r] = upk(ab1p, r); ah1[r] = upk(ab1p, 16 + r); }
            #pragma unroll
            for (int kt = 0; kt < 2; kt++) {
                ah0 = __builtin_amdgcn_mfma_f32_32x32x16_bf16(fw_aw1[0][kt].v, fu[kt].v, ah0, 0, 0, 0);
                ah1 = __builtin_amdgcn_mfma_f32_32x32x16_bf16(fw_aw1[1][kt].v, fu[kt].v, ah1, 0, 0, 0);
            }
            FragU fh[4];
            #pragma unroll
            for (int q = 0; q < 4; q++)
                #pragma unroll
                for (int jw = 0; jw < 4; jw++) {
                    int r0 = 8*(q&1) + 2*jw;
                    float x0 = (q < 2) ? ah0[r0]   : ah1[r0];
                    float x1 = (q < 2) ? ah0[r0+1] : ah1[r0+1];
                    fh[q].w[jw] = pk2(fmaxf(x0, 0.f), fmaxf(x1, 0.f));
                }
            f32x16 aa;
            #pragma unroll
            for (int r = 0; r < 16; r++) aa[r] = upk(ab2p, r);
            aa = __builtin_amdgcn_mfma_f32_32x32x16_bf16(fw_aw2[0].v, fh[0].v, aa, 0, 0, 0);
            aa = __builtin_amdgcn_mfma_f32_32x32x16_bf16(fw_aw2[1].v, fh[1].v, aa, 0, 0, 0);
            aa = __builtin_amdgcn_mfma_f32_32x32x16_bf16(fw_aw2[2].v, fh[2].v, aa, 0, 0, 0);
            aa = __builtin_amdgcn_mfma_f32_32x32x16_bf16(fw_aw2[3].v, fh[3].v, aa, 0, 0, 0);
            if (SORTED) {
                int lw = lane & 31;
                int dprev = __shfl_up(dst, 1, 32);
                bool isHead = (lw == 0) || (dprev != dst);
                bool eq1  = (__shfl_down(dst, 1, 32)  == dst) && (lw + 1  < 32);
                bool eq2  = (__shfl_down(dst, 2, 32)  == dst) && (lw + 2  < 32);
                bool eq4  = (__shfl_down(dst, 4, 32)  == dst) && (lw + 4  < 32);
                bool eq8  = (__shfl_down(dst, 8, 32)  == dst) && (lw + 8  < 32);
                bool eq16 = (__shfl_down(dst, 16, 32) == dst) && (lw + 16 < 32);
                float* drow = denom + (size_t)dst * 32;
                float* orow = outp  + (size_t)dst * 32;
                #pragma unroll
                for (int r = 0; r < 16; r++) {
                    float ea = __expf(fminf(aa[r], 35.f));
                    float ev = valid ? ea : 0.f;
                    float mv = valid ? ea * (xg[r] + adl[r]) : 0.f;
                    { float a = __shfl_down(ev,1,32),  b = __shfl_down(mv,1,32);  if (eq1)  { ev += a; mv += b; } }
                    { float a = __shfl_down(ev,2,32),  b = __shfl_down(mv,2,32);  if (eq2)  { ev += a; mv += b; } }
                    { float a = __shfl_down(ev,4,32),  b = __shfl_down(mv,4,32);  if (eq4)  { ev += a; mv += b; } }
                    { float a = __shfl_down(ev,8,32),  b = __shfl_down(mv,8,32);  if (eq8)  { ev += a; mv += b; } }
                    { float a = __shfl_down(ev,16,32), b = __shfl_down(mv,16,32); if (eq16) { ev += a; mv += b; } }
                    if (isHead) {
                        int o = rowv[r];
                        unsafeAtomicAdd(drow + o, ev);
                        unsafeAtomicAdd(orow + o, mv);
                    }
                }
            } else if (valid) {
                float* drow = denom + (size_t)dst * 32;
                float* orow = outp  + (size_t)dst * 32;
                #pragma unroll
                for (int r = 0; r < 16; r++) {
                    int o = rowv[r];
                    float ea = __expf(fminf(aa[r], 35.f));
                    unsafeAtomicAdd(drow + o, ea);
                    unsafeAtomicAdd(orow + o, ea * (xg[r] + adl[r]));
                }
            }
        }
    }
}

// ---------- pass 3: out /= (denom + 1e-16) ----------
__global__ __launch_bounds__(256) void k_norm(
    float* __restrict__ out, const float* __restrict__ denom, int total)
{
    int i = blockIdx.x * 256 + threadIdx.x;
    if (i < total) out[i] = out[i] / (denom[i] + 1e-16f);
}

extern "C" void kernel_launch(void* const* d_in, const int* in_sizes, int n_in,
                              void* d_out, int out_size, void* d_ws, size_t ws_size,
                              hipStream_t stream)
{
    const float* x     = (const float*)d_in[0];
    const float* pos   = (const float*)d_in[1];
    const int*   ei    = (const int*)d_in[2];
    const float* w_lin = (const float*)d_in[3];
    const float* w_src = (const float*)d_in[4];
    const float* w_dst = (const float*)d_in[5];
    const float* pw1   = (const float*)d_in[6];
    const float* pb1   = (const float*)d_in[7];
    const float* pg    = (const float*)d_in[8];
    const float* pbeta = (const float*)d_in[9];
    const float* pw2   = (const float*)d_in[10];
    const float* pb2   = (const float*)d_in[11];
    const float* aw1   = (const float*)d_in[12];
    const float* ab1   = (const float*)d_in[13];
    const float* ag    = (const float*)d_in[14];
    const float* abeta = (const float*)d_in[15];
    const float* aw2   = (const float*)d_in[16];
    const float* ab2   = (const float*)d_in[17];
    float* out = (float*)d_out;

    const int nNodes = in_sizes[0] / 64;
    const int nE     = in_sizes[2] / 2;
    const int eTot   = nE + nNodes;

    const int PMBLK = 1024;
    const int DBLK  = 2048;

    const size_t nF = (size_t)nNodes * 32;
    uint*   asx   = (uint*)d_ws;                        // nNodes*32 uints (aS|xv 128B rows)
    uint*   aDb   = asx + (size_t)nNodes*32;            // nNodes*16 uints
    float*  pos4  = (float*)(aDb + (size_t)nNodes*16);  // nNodes*4
    float*  denom = pos4 + (size_t)nNodes*4;            // nF
    float*  stats = denom + nF;                         // 512
    float*  bn1   = stats + 512;
    float*  bn2   = bn1 + 128;
    float*  pw1f  = bn2 + 128;
    float*  pb1f  = pw1f + 192;
    float*  aw1f  = pb1f + 64;
    float*  ab1f  = aw1f + 2048;
    float*  partM = ab1f + 64;
    float*  partD = partM + (size_t)PMBLK*9;
    float*  fend  = partD + (size_t)DBLK*128;

    int* cnt    = (int*)fend;
    int* cur    = cnt + nNodes;
    int* blkS   = cur + nNodes;
    int* blkOff = blkS + 256;
    int* srcs   = blkOff + 256;
    int* dsts   = srcs + eTot;

    size_t need_sorted = (char*)(dsts + eTot) - (char*)d_ws;
    const bool sorted = ws_size >= need_sorted;

    const int nb = (nNodes + SCH - 1) / SCH;

    hipMemsetAsync(out,   0, nF * sizeof(float), stream);
    hipMemsetAsync(denom, 0, nF * sizeof(float), stream);

    k_node_lin<<<(nNodes + 255) / 256, 256, 0, stream>>>(
        x, w_src, w_dst, w_lin, asx, aDb, nNodes);
    k_pos4<<<(nNodes + 255) / 256, 256, 0, stream>>>(pos, (float4*)pos4, nNodes);

    k_pos_mom<<<PMBLK, 256, 0, stream>>>(ei, (const float4*)pos4, partM, nE);
    k_bn1_mom<<<1, 64, 0, stream>>>(partM, PMBLK, pw1, pb1, pg, pbeta, bn1,
                                    1.0f / (float)eTot);
    k_fold1<<<1, 256, 0, stream>>>(pw1, pb1, bn1, pw1f, pb1f);

    if (sorted) {
        hipMemsetAsync(cnt, 0, (size_t)nNodes * sizeof(int), stream);
        k_hist<<<(eTot + 255) / 256, 256, 0, stream>>>(ei, cnt, nE, eTot);
        k_scan1<<<nb, 256, 0, stream>>>(cnt, cur, blkS, nNodes);
        k_scan2<<<1, 256, 0, stream>>>(blkS, blkOff, nb);
        k_scan3<<<nb, 256, 0, stream>>>(cur, blkOff, nNodes);
        k_rank<<<(eTot + 255) / 256, 256, 0, stream>>>(ei, cur, srcs, dsts, nE, eTot);

        k_delta_stats<true><<<DBLK, 256, 0, stream>>>(
            ei, srcs, dsts, (const float4*)pos4, asx, aDb,
            pw1f, pb1f, pw2, pb2, aw1, partD, nE, eTot);
        k_red_stats<<<128, 256, 0, stream>>>(partD, stats + 128, DBLK);
        k_bn_fin<<<1, 64, 0, stream>>>(stats + 128, ag, abeta, ab1, bn2, 1.0f / (float)eTot);
        k_fold2<<<8, 256, 0, stream>>>(aw1, ab1, bn2, aw1f, ab1f);
        k_att_agg<true><<<DBLK, 256, 0, stream>>>(
            ei, srcs, dsts, (const float4*)pos4, asx, aDb,
            pw1f, pb1f, pw2, pb2, aw1f, ab1f, aw2, ab2, denom, out, nE, eTot);
    } else {
        k_delta_stats<false><<<DBLK, 256, 0, stream>>>(
            ei, nullptr, nullptr, (const float4*)pos4, asx, aDb,
            pw1f, pb1f, pw2, pb2, aw1, partD, nE, eTot);
        k_red_stats<<<128, 256, 0, stream>>>(partD, stats + 128, DBLK);
        k_bn_fin<<<1, 64, 0, stream>>>(stats + 128, ag, abeta, ab1, bn2, 1.0f / (float)eTot);
        k_fold2<<<8, 256, 0, stream>>>(aw1, ab1, bn2, aw1f, ab1f);
        k_att_agg<false><<<DBLK, 256, 0, stream>>>(
            ei, nullptr, nullptr, (const float4*)pos4, asx, aDb,
            pw1f, pb1f, pw2, pb2, aw1f, ab1f, aw2, ab2, denom, out, nE, eTot);
    }
    k_norm<<<(((int)nF) + 255) / 256, 256, 0, stream>>>(out, denom, (int)nF);
}

// Round 16
// 812.113 us; speedup vs baseline: 1.0646x; 1.0646x over previous
//
#include <hip/hip_runtime.h>

typedef unsigned int uint;
typedef unsigned short ushort;

#define BN_EPS 1e-5f

using bf16x8 = __attribute__((ext_vector_type(8))) short;
using f32x16 = __attribute__((ext_vector_type(16))) float;

union FragU { uint w[4]; bf16x8 v; };

__device__ __forceinline__ uint pk2(float lo, float hi) {
    uint r;
    asm("v_cvt_pk_bf16_f32 %0, %1, %2" : "=v"(r) : "v"(lo), "v"(hi));
    return r;
}
__device__ __forceinline__ float bfu_lo(uint u) { return __uint_as_float(u << 16); }
__device__ __forceinline__ float bfu_hi(uint u) { return __uint_as_float(u & 0xffff0000u); }

__device__ __forceinline__ float upk(const uint* p, int idx) {
    uint u = p[idx >> 1];
    return (idx & 1) ? bfu_hi(u) : bfu_lo(u);
}
__device__ __forceinline__ float upq(const uint2* gq, int r) {
    int g = r >> 2, j = r & 3;
    uint u = (j < 2) ? gq[g].x : gq[g].y;
    return (j & 1) ? bfu_hi(u) : bfu_lo(u);
}

// Self-calibration: true D-reg -> row mapping of mfma_f32_32x32x16_bf16.
__device__ __forceinline__ void get_rowmap(int col, int* rowv) {
    FragU pa, pb;
    float c = (float)col;
    #pragma unroll
    for (int j = 0; j < 4; j++) { pa.w[j] = pk2(c, c); pb.w[j] = pk2(1.f, 1.f); }
    f32x16 d;
    #pragma unroll
    for (int r = 0; r < 16; r++) d[r] = 0.f;
    d = __builtin_amdgcn_mfma_f32_32x32x16_bf16(pa.v, pb.v, d, 0, 0, 0);
    #pragma unroll
    for (int r = 0; r < 16; r++) {
        int m = (int)(d[r] * 0.0625f + 0.5f);
        rowv[r] = (m < 0) ? 0 : (m > 31 ? 31 : m);
    }
}

template<bool SORTED>
__device__ __forceinline__ void edge_sd(int e, const int* __restrict__ ei,
                                        const int* __restrict__ srcs,
                                        const int* __restrict__ dsts,
                                        int nE, int& src, int& dst) {
    if (SORTED) { src = srcs[e]; dst = dsts[e]; }
    else if (e < nE) { src = ei[e]; dst = ei[nE + e]; }
    else { src = e - nE; dst = src; }
}

// ---------- node linears -> asx: interleaved [aS(16u) | xv(16u)] 128B rows; aDb separate ----------
__global__ __launch_bounds__(256) void k_node_lin(
    const float* __restrict__ x,
    const float* __restrict__ w_src, const float* __restrict__ w_dst,
    const float* __restrict__ w_lin,
    uint* __restrict__ asx, uint* __restrict__ aDb,
    int nNodes)
{
    int n = blockIdx.x * 256 + threadIdx.x;
    if (n >= nNodes) return;
    float xr[64];
    const float4* xp = (const float4*)(x + (size_t)n * 64);
    #pragma unroll
    for (int i = 0; i < 16; i++) {
        float4 v = xp[i];
        xr[4*i] = v.x; xr[4*i+1] = v.y; xr[4*i+2] = v.z; xr[4*i+3] = v.w;
    }
    const float* ws[3] = { w_src, w_lin, w_dst };
    uint* outs[3] = { asx + (size_t)n*32, asx + (size_t)n*32 + 16, aDb + (size_t)n*16 };
    #pragma unroll
    for (int m = 0; m < 3; m++) {
        const float* w = ws[m];
        float acc[32];
        #pragma unroll
        for (int o = 0; o < 32; o++) acc[o] = 0.f;
        #pragma unroll
        for (int k = 0; k < 64; k++) {
            float xk = xr[k];
            #pragma unroll
            for (int o = 0; o < 32; o++) acc[o] = fmaf(xk, w[k*32+o], acc[o]);
        }
        uint4* op = (uint4*)outs[m];
        #pragma unroll
        for (int q = 0; q < 4; q++) {
            uint4 v;
            v.x = pk2(acc[8*q+0], acc[8*q+1]);
            v.y = pk2(acc[8*q+2], acc[8*q+3]);
            v.z = pk2(acc[8*q+4], acc[8*q+5]);
            v.w = pk2(acc[8*q+6], acc[8*q+7]);
            op[q] = v;
        }
    }
}

// ---------- pos -> float4 ----------
__global__ __launch_bounds__(256) void k_pos4(
    const float* __restrict__ pos, float4* __restrict__ pos4, int n)
{
    int i = blockIdx.x * 256 + threadIdx.x;
    if (i < n) pos4[i] = make_float4(pos[i*3], pos[i*3+1], pos[i*3+2], 0.f);
}

// ---------- sort-by-dst ----------
__global__ __launch_bounds__(256) void k_hist(
    const int* __restrict__ ei, int* __restrict__ cnt, int nE, int eTot)
{
    int e = blockIdx.x * 256 + threadIdx.x;
    if (e >= eTot) return;
    int dst = (e < nE) ? ei[nE + e] : (e - nE);
    atomicAdd(&cnt[dst], 1);
}

#define SCH 1024
__global__ __launch_bounds__(256) void k_scan1(
    const int* __restrict__ cnt, int* __restrict__ cur,
    int* __restrict__ blkS, int n)
{
    __shared__ int ls[256];
    int t = threadIdx.x;
    int base = blockIdx.x * SCH + t * 4;
    int v0 = (base+0 < n) ? cnt[base+0] : 0;
    int v1 = (base+1 < n) ? cnt[base+1] : 0;
    int v2 = (base+2 < n) ? cnt[base+2] : 0;
    int v3 = (base+3 < n) ? cnt[base+3] : 0;
    int tsum = v0 + v1 + v2 + v3;
    ls[t] = tsum;
    __syncthreads();
    for (int o = 1; o < 256; o <<= 1) {
        int x = (t >= o) ? ls[t-o] : 0;
        __syncthreads();
        ls[t] += x;
        __syncthreads();
    }
    if (t == 255) blkS[blockIdx.x] = ls[255];
    int run = ls[t] - tsum;
    if (base+0 < n) cur[base+0] = run; run += v0;
    if (base+1 < n) cur[base+1] = run; run += v1;
    if (base+2 < n) cur[base+2] = run; run += v2;
    if (base+3 < n) cur[base+3] = run;
}

__global__ void k_scan2(const int* __restrict__ blkS, int* __restrict__ blkOff, int nb)
{
    __shared__ int ls[256];
    int t = threadIdx.x;
    int v = (t < nb) ? blkS[t] : 0;
    ls[t] = v;
    __syncthreads();
    for (int o = 1; o < 256; o <<= 1) {
        int x = (t >= o) ? ls[t-o] : 0;
        __syncthreads();
        ls[t] += x;
        __syncthreads();
    }
    if (t < nb) blkOff[t] = ls[t] - v;
}

__global__ __launch_bounds__(256) void k_scan3(
    int* __restrict__ cur, const int* __restrict__ blkOff, int n)
{
    int off = blkOff[blockIdx.x];
    int base = blockIdx.x * SCH + threadIdx.x * 4;
    #pragma unroll
    for (int j = 0; j < 4; j++) {
        int i = base + j;
        if (i < n) cur[i] += off;
    }
}

__global__ __launch_bounds__(256) void k_rank(
    const int* __restrict__ ei, int* __restrict__ cur,
    int* __restrict__ srcs, int* __restrict__ dsts, int nE, int eTot)
{
    int e = blockIdx.x * 256 + threadIdx.x;
    if (e >= eTot) return;
    int src, dst;
    if (e < nE) { src = ei[e]; dst = ei[nE + e]; }
    else        { src = e - nE; dst = src; }
    int slot = atomicAdd(&cur[dst], 1);
    srcs[slot] = src; dsts[slot] = dst;
}

// ---------- pass 0: 9 moments of d (block partials) ----------
__global__ __launch_bounds__(256) void k_pos_mom(
    const int* __restrict__ ei, const float4* __restrict__ pos4,
    float* __restrict__ partM, int nE)
{
    float m[9];
    #pragma unroll
    for (int c = 0; c < 9; c++) m[c] = 0.f;
    int stride = gridDim.x * blockDim.x;
    for (int e = blockIdx.x * blockDim.x + threadIdx.x; e < nE; e += stride) {
        int src = ei[e], dst = ei[nE + e];
        float4 pd = pos4[dst], ps = pos4[src];
        float d0 = pd.x - ps.x, d1 = pd.y - ps.y, d2 = pd.z - ps.z;
        m[0] += d0; m[1] += d1; m[2] += d2;
        m[3] = fmaf(d0,d0,m[3]); m[4] = fmaf(d0,d1,m[4]); m[5] = fmaf(d0,d2,m[5]);
        m[6] = fmaf(d1,d1,m[6]); m[7] = fmaf(d1,d2,m[7]); m[8] = fmaf(d2,d2,m[8]);
    }
    __shared__ float red[4][9];
    int w = threadIdx.x >> 6;
    #pragma unroll
    for (int c = 0; c < 9; c++) {
        float t = m[c];
        for (int o = 32; o > 0; o >>= 1) t += __shfl_down(t, o, 64);
        if ((threadIdx.x & 63) == 0) red[w][c] = t;
    }
    __syncthreads();
    if (threadIdx.x < 9)
        partM[blockIdx.x * 9 + threadIdx.x] =
            red[0][threadIdx.x] + red[1][threadIdx.x] + red[2][threadIdx.x] + red[3][threadIdx.x];
}

__global__ void k_bn1_mom(const float* __restrict__ partM, int nBlk,
                          const float* __restrict__ pw1, const float* __restrict__ pb1,
                          const float* __restrict__ g, const float* __restrict__ beta,
                          float* __restrict__ bn, float invE)
{
    __shared__ float mom_s[9];
    int l = threadIdx.x;
    #pragma unroll
    for (int c = 0; c < 9; c++) {
        float s = 0.f;
        for (int i = l; i < nBlk; i += 64) s += partM[i*9 + c];
        for (int o = 32; o > 0; o >>= 1) s += __shfl_down(s, o, 64);
        if (l == 0) mom_s[c] = s;
    }
    __syncthreads();
    int c = l;
    if (c < 64) {
        float w0 = pw1[c], w1 = pw1[64+c], w2 = pw1[128+c], b = pb1[c];
        float S = fmaf(w0, mom_s[0], fmaf(w1, mom_s[1], w2 * mom_s[2]));
        float Q = w0*w0*mom_s[3] + 2.f*w0*w1*mom_s[4] + 2.f*w0*w2*mom_s[5]
                + w1*w1*mom_s[6] + 2.f*w1*w2*mom_s[7] + w2*w2*mom_s[8];
        float mu  = S * invE + b;
        float E2  = Q * invE + 2.f * b * (S * invE) + b * b;
        float var = fmaxf(E2 - mu * mu, 0.f);
        float sc  = rsqrtf(var + BN_EPS) * g[c];
        bn[c]      = sc;
        bn[64+c]   = beta[c] - mu * sc;
    }
}

__global__ __launch_bounds__(256) void k_red_stats(
    const float* __restrict__ partD, float* __restrict__ stats2, int nBlk)
{
    int c = blockIdx.x;  // 0..127
    float s = 0.f;
    for (int i = threadIdx.x; i < nBlk; i += 256) s += partD[(size_t)i*128 + c];
    for (int o = 32; o > 0; o >>= 1) s += __shfl_down(s, o, 64);
    __shared__ float red[4];
    if ((threadIdx.x & 63) == 0) red[threadIdx.x >> 6] = s;
    __syncthreads();
    if (threadIdx.x == 0) stats2[c] = red[0] + red[1] + red[2] + red[3];
}

__global__ void k_bn_fin(const float* __restrict__ stats,
                         const float* __restrict__ g, const float* __restrict__ beta,
                         const float* __restrict__ bias,
                         float* __restrict__ bn, float inv_ep)
{
    int c = threadIdx.x;
    if (c < 64) {
        float b   = bias ? bias[c] : 0.f;
        float m0  = stats[c] * inv_ep;
        float mu  = m0 + b;
        float eq  = stats[64+c] * inv_ep + 2.f*b*m0 + b*b;
        float var = fmaxf(eq - mu * mu, 0.f);
        float sc  = rsqrtf(var + BN_EPS) * g[c];
        bn[c]      = sc;
        bn[64+c]   = beta[c] - mu * sc;
    }
}

__global__ void k_fold1(const float* __restrict__ pw1, const float* __restrict__ pb1,
                        const float* __restrict__ bn1,
                        float* __restrict__ pw1f, float* __restrict__ pb1f)
{
    int i = threadIdx.x;
    if (i < 192) pw1f[i] = pw1[i] * bn1[i & 63];
    if (i < 64)  pb1f[i] = pb1[i] * bn1[i] + bn1[64 + i];
}

__global__ void k_fold2(const float* __restrict__ aw1, const float* __restrict__ ab1,
                        const float* __restrict__ bn2,
                        float* __restrict__ aw1f, float* __restrict__ ab1f)
{
    int i = blockIdx.x * 256 + threadIdx.x;
    if (i < 2048) aw1f[i] = aw1[i] * bn2[i & 63];
    if (i < 64)   ab1f[i] = ab1[i] * bn2[i] + bn2[64 + i];
}

// ---------- pass 1: delta + raw h2 stats (direct gathers, block partials) ----------
template<bool SORTED>
__global__ __launch_bounds__(256, 2) void k_delta_stats(
    const int* __restrict__ ei, const int* __restrict__ srcs, const int* __restrict__ dsts,
    const float4* __restrict__ pos4,
    const uint* __restrict__ asx, const uint* __restrict__ aDb,
    const float* __restrict__ pw1f, const float* __restrict__ pb1f,
    const float* __restrict__ pw2, const float* __restrict__ pb2,
    const float* __restrict__ aw1,
    float* __restrict__ partD, int nE, int eTot)
{
    const int lane = threadIdx.x & 63;
    const int col  = lane & 31;
    const int h    = lane >> 5;

    __shared__ float redS[4][64], redQ[4][64];
    {
        int w = threadIdx.x >> 6, c = threadIdx.x & 63;
        redS[w][c] = 0.f; redQ[w][c] = 0.f;
    }

    bool quadOK;
    int q2[4];
    FragU fw_pw2[4];
    FragU fw_aw1[2][2];
    uint pb2p[8];
    int rowv[16];
    {
        get_rowmap(col, rowv);
        quadOK = true;
        #pragma unroll
        for (int g = 0; g < 4; g++)
            quadOK = quadOK && (rowv[4*g+1] == rowv[4*g]+1)
                            && (rowv[4*g+2] == rowv[4*g]+2)
                            && (rowv[4*g+3] == rowv[4*g]+3);
        #pragma unroll
        for (int g = 0; g < 4; g++) q2[g] = rowv[4*g] >> 2;
        #pragma unroll
        for (int kt = 0; kt < 4; kt++)
            #pragma unroll
            for (int jw = 0; jw < 4; jw++) {
                int m = 2*jw;
                int c0 = 16*kt + 8*(m>>2) + 4*h + (m&3);
                fw_pw2[kt].w[jw] = pk2(pw2[c0*32 + col], pw2[(c0+1)*32 + col]);
            }
        #pragma unroll
        for (int mt = 0; mt < 2; mt++)
            #pragma unroll
            for (int kt = 0; kt < 2; kt++)
                #pragma unroll
                for (int jw = 0; jw < 4; jw++) {
                    int u0 = rowv[8*kt + 2*jw], u1 = rowv[8*kt + 2*jw + 1];
                    fw_aw1[mt][kt].w[jw] = pk2(aw1[u0*64 + 32*mt + col],
                                               aw1[u1*64 + 32*mt + col]);
                }
        #pragma unroll
        for (int g = 0; g < 8; g++)
            pb2p[g] = pk2(pb2[rowv[2*g]], pb2[rowv[2*g+1]]);
    }

    float sA[32], qA[32];
    #pragma unroll
    for (int i = 0; i < 32; i++) { sA[i] = 0.f; qA[i] = 0.f; }

    const int nT = (eTot + 31) >> 5;
    const int gw = (blockIdx.x << 2) + (threadIdx.x >> 6);
    const int nW = gridDim.x << 2;

    for (int t = gw; t < nT; t += nW) {
        int e = t*32 + col;
        bool valid = e < eTot;
        int ec = valid ? e : eTot - 1;
        int src, dst;
        edge_sd<SORTED>(ec, ei, srcs, dsts, nE, src, dst);
        float4 ps = pos4[src], pd = pos4[dst];
        float p0 = pd.x - ps.x, p1 = pd.y - ps.y, p2 = pd.z - ps.z;

        // direct gathers (issued early)
        uint2 gs2[4], gd2[4];
        float gSs[16], gDs[16];
        if (quadOK) {
            const uint* rs = asx + (size_t)src*32;
            const uint* rd = aDb + (size_t)dst*16;
            #pragma unroll
            for (int g = 0; g < 4; g++) gs2[g] = *(const uint2*)(rs + 2*q2[g]);
            #pragma unroll
            for (int g = 0; g < 4; g++) gd2[g] = *(const uint2*)(rd + 2*q2[g]);
        } else {
            const ushort* rs = (const ushort*)(asx + (size_t)src*32);
            const ushort* rd = (const ushort*)(aDb + (size_t)dst*16);
            #pragma unroll
            for (int r = 0; r < 16; r++) {
                gSs[r] = __uint_as_float(((uint)rs[rowv[r]]) << 16);
                gDs[r] = __uint_as_float(((uint)rd[rowv[r]]) << 16);
            }
        }

        FragU ft[4];
        #pragma unroll
        for (int kt = 0; kt < 4; kt++)
            #pragma unroll
            for (int mm = 0; mm < 2; mm++) {
                int cb = 16*kt + 8*mm + 4*h;
                float4 w0 = *(const float4*)(pw1f +       cb);
                float4 w1 = *(const float4*)(pw1f + 64  + cb);
                float4 w2 = *(const float4*)(pw1f + 128 + cb);
                float4 bb = *(const float4*)(pb1f + cb);
                float t0 = fmaxf(fmaf(p0,w0.x, fmaf(p1,w1.x, fmaf(p2,w2.x, bb.x))), 0.f);
                float t1 = fmaxf(fmaf(p0,w0.y, fmaf(p1,w1.y, fmaf(p2,w2.y, bb.y))), 0.f);
                float t2 = fmaxf(fmaf(p0,w0.z, fmaf(p1,w1.z, fmaf(p2,w2.z, bb.z))), 0.f);
                float t3 = fmaxf(fmaf(p0,w0.w, fmaf(p1,w1.w, fmaf(p2,w2.w, bb.w))), 0.f);
                ft[kt].w[2*mm+0] = pk2(t0, t1);
                ft[kt].w[2*mm+1] = pk2(t2, t3);
            }
        f32x16 adl;
        #pragma unroll
        for (int r = 0; r < 16; r++) adl[r] = upk(pb2p, r);
        #pragma unroll
        for (int kt = 0; kt < 4; kt++)
            adl = __builtin_amdgcn_mfma_f32_32x32x16_bf16(fw_pw2[kt].v, ft[kt].v, adl, 0, 0, 0);

        FragU fu[2];
        if (quadOK) {
            #pragma unroll
            for (int kt = 0; kt < 2; kt++)
                #pragma unroll
                for (int jw = 0; jw < 4; jw++) {
                    int r0 = 8*kt + 2*jw;
                    fu[kt].w[jw] = pk2(adl[r0]   + upq(gd2, r0)   - upq(gs2, r0),
                                       adl[r0+1] + upq(gd2, r0+1) - upq(gs2, r0+1));
                }
        } else {
            #pragma unroll
            for (int kt = 0; kt < 2; kt++)
                #pragma unroll
                for (int jw = 0; jw < 4; jw++) {
                    int r0 = 8*kt + 2*jw;
                    fu[kt].w[jw] = pk2(adl[r0]   + gDs[r0]   - gSs[r0],
                                       adl[r0+1] + gDs[r0+1] - gSs[r0+1]);
                }
        }

        f32x16 ah0, ah1;
        #pragma unroll
        for (int r = 0; r < 16; r++) { ah0[r] = 0.f; ah1[r] = 0.f; }
        #pragma unroll
        for (int kt = 0; kt < 2; kt++) {
            ah0 = __builtin_amdgcn_mfma_f32_32x32x16_bf16(fw_aw1[0][kt].v, fu[kt].v, ah0, 0, 0, 0);
            ah1 = __builtin_amdgcn_mfma_f32_32x32x16_bf16(fw_aw1[1][kt].v, fu[kt].v, ah1, 0, 0, 0);
        }
        if (valid) {
            #pragma unroll
            for (int r = 0; r < 16; r++) {
                sA[r]    += ah0[r];
                qA[r]     = fmaf(ah0[r], ah0[r], qA[r]);
                sA[16+r] += ah1[r];
                qA[16+r]  = fmaf(ah1[r], ah1[r], qA[16+r]);
            }
        }
    }

    __syncthreads();
    {
        int w = threadIdx.x >> 6;
        #pragma unroll
        for (int idx = 0; idx < 32; idx++) {
            float vs = sA[idx], vq = qA[idx];
            for (int off = 16; off > 0; off >>= 1) {
                vs += __shfl_xor(vs, off, 64);
                vq += __shfl_xor(vq, off, 64);
            }
            if ((threadIdx.x & 31) == 0) {
                int mt = idx >> 4, r = idx & 15;
                int c = 32*mt + rowv[r];
                redS[w][c] = vs;
                redQ[w][c] = vq;
            }
        }
    }
    __syncthreads();
    if (threadIdx.x < 64) {
        int c = threadIdx.x;
        float S = redS[0][c] + redS[1][c] + redS[2][c] + redS[3][c];
        float Q = redQ[0][c] + redQ[1][c] + redQ[2][c] + redQ[3][c];
        partD[(size_t)blockIdx.x*128 + c]      = S;
        partD[(size_t)blockIdx.x*128 + 64 + c] = Q;
    }
}

// ---------- pass 2: LDS-staged src gathers with T14 issue-early/write-late pipeline ----------
template<bool SORTED>
__global__ __launch_bounds__(256, 2) void k_att_agg(
    const int* __restrict__ ei, const int* __restrict__ srcs, const int* __restrict__ dsts,
    const float4* __restrict__ pos4,
    const uint* __restrict__ asx, const uint* __restrict__ aDb,
    const float* __restrict__ pw1f, const float* __restrict__ pb1f,
    const float* __restrict__ pw2, const float* __restrict__ pb2,
    const float* __restrict__ aw1f, const float* __restrict__ ab1f,
    const float* __restrict__ aw2, const float* __restrict__ ab2,
    float* __restrict__ denom, float* __restrict__ outp,
    int nE, int eTot)
{
    const int lane = threadIdx.x & 63;
    const int col  = lane & 31;
    const int h    = lane >> 5;
    const int wid  = threadIdx.x >> 6;

    __shared__ uint sbuf[4][1024];   // per-wave 32 rows x 32 uints (swizzled)

    bool quadOK;
    int q2[4];
    int rowv[16];
    FragU fw_pw2[4], fw_aw2[4];
    FragU fw_aw1[2][2];
    uint pb2p[8], ab2p[8], ab1p[16];
    {
        get_rowmap(col, rowv);
        quadOK = true;
        #pragma unroll
        for (int g = 0; g < 4; g++)
            quadOK = quadOK && (rowv[4*g+1] == rowv[4*g]+1)
                            && (rowv[4*g+2] == rowv[4*g]+2)
                            && (rowv[4*g+3] == rowv[4*g]+3);
        #pragma unroll
        for (int g = 0; g < 4; g++) q2[g] = rowv[4*g] >> 2;
        #pragma unroll
        for (int kt = 0; kt < 4; kt++)
            #pragma unroll
            for (int jw = 0; jw < 4; jw++) {
                int m = 2*jw;
                int c0 = 16*kt + 8*(m>>2) + 4*h + (m&3);
                fw_pw2[kt].w[jw] = pk2(pw2[c0*32 + col], pw2[(c0+1)*32 + col]);
                int o0 = 32*(kt>>1) + rowv[8*(kt&1) + m];
                int o1 = 32*(kt>>1) + rowv[8*(kt&1) + m + 1];
                fw_aw2[kt].w[jw] = pk2(aw2[o0*32 + col], aw2[o1*32 + col]);
            }
        #pragma unroll
        for (int mt = 0; mt < 2; mt++)
            #pragma unroll
            for (int kt = 0; kt < 2; kt++)
                #pragma unroll
                for (int jw = 0; jw < 4; jw++) {
                    int u0 = rowv[8*kt + 2*jw], u1 = rowv[8*kt + 2*jw + 1];
                    fw_aw1[mt][kt].w[jw] = pk2(aw1f[u0*64 + 32*mt + col],
                                               aw1f[u1*64 + 32*mt + col]);
                }
        #pragma unroll
        for (int g = 0; g < 8; g++) {
            pb2p[g] = pk2(pb2[rowv[2*g]], pb2[rowv[2*g+1]]);
            ab2p[g] = pk2(ab2[rowv[2*g]], ab2[rowv[2*g+1]]);
            ab1p[g]     = pk2(ab1f[rowv[2*g]],      ab1f[rowv[2*g+1]]);
            ab1p[8 + g] = pk2(ab1f[32 + rowv[2*g]], ab1f[32 + rowv[2*g+1]]);
        }
    }

    const int nT = (eTot + 31) >> 5;
    const int gw = (blockIdx.x << 2) + (threadIdx.x >> 6);
    const int nW = gridDim.x << 2;

    if (quadOK) {
        // ---- T14 pipeline: fetch tile inputs into regs early; ds_write at use time ----
        int c_src, c_dst; float4 c_ps, c_pd; uint4 c_sv0, c_sv1, c_sv2, c_sv3;
        int t = gw;
        if (t < nT) {
            int e = t*32 + col;
            int ec = (e < eTot) ? e : eTot - 1;
            edge_sd<SORTED>(ec, ei, srcs, dsts, nE, c_src, c_dst);
            c_ps = pos4[c_src]; c_pd = pos4[c_dst];
            int w = lane & 7;
            #define LDSTG(it, dstv) { int j = (it)*8 + (lane >> 3); int sj = __shfl(c_src, j, 64); \
                dstv = *(const uint4*)(asx + (size_t)sj*32 + w*4); }
            LDSTG(0, c_sv0) LDSTG(1, c_sv1) LDSTG(2, c_sv2) LDSTG(3, c_sv3)
            #undef LDSTG
        }
        for (; t < nT; ) {
            // write staged rows for current tile
            {
                int w = lane & 7;
                #define STSTG(it, srcv) { int j = (it)*8 + (lane >> 3); \
                    *(uint4*)&sbuf[wid][j*32 + ((w ^ (j & 7)) << 2)] = srcv; }
                STSTG(0, c_sv0) STSTG(1, c_sv1) STSTG(2, c_sv2) STSTG(3, c_sv3)
                #undef STSTG
            }
            int src = c_src, dst = c_dst;
            bool valid = (t*32 + col) < eTot;
            float p0 = c_pd.x - c_ps.x, p1 = c_pd.y - c_ps.y, p2 = c_pd.z - c_ps.z;

            // issue NEXT tile's global loads (overlap with compute below)
            int tn = t + nW;
            int tc = (tn < nT) ? tn : t;
            int n_src, n_dst; float4 n_ps, n_pd; uint4 n_sv0, n_sv1, n_sv2, n_sv3;
            {
                int e2 = tc*32 + col;
                int ec2 = (e2 < eTot) ? e2 : eTot - 1;
                edge_sd<SORTED>(ec2, ei, srcs, dsts, nE, n_src, n_dst);
                n_ps = pos4[n_src]; n_pd = pos4[n_dst];
                int w = lane & 7;
                #define LDSTG(it, dstv) { int j = (it)*8 + (lane >> 3); int sj = __shfl(n_src, j, 64); \
                    dstv = *(const uint4*)(asx + (size_t)sj*32 + w*4); }
                LDSTG(0, n_sv0) LDSTG(1, n_sv1) LDSTG(2, n_sv2) LDSTG(3, n_sv3)
                #undef LDSTG
            }

            // dst-row gather (run-local, L1-friendly)
            uint2 gd2[4];
            {
                const uint* rd = aDb + (size_t)dst*16;
                #pragma unroll
                for (int g = 0; g < 4; g++) gd2[g] = *(const uint2*)(rd + 2*q2[g]);
            }

            FragU ft[4];
            #pragma unroll
            for (int kt = 0; kt < 4; kt++)
                #pragma unroll
                for (int mm = 0; mm < 2; mm++) {
                    int cb = 16*kt + 8*mm + 4*h;
                    float4 w0 = *(const float4*)(pw1f +       cb);
                    float4 w1 = *(const float4*)(pw1f + 64  + cb);
                    float4 w2 = *(const float4*)(pw1f + 128 + cb);
                    float4 bb = *(const float4*)(pb1f + cb);
                    float t0 = fmaxf(fmaf(p0,w0.x, fmaf(p1,w1.x, fmaf(p2,w2.x, bb.x))), 0.f);
                    float t1 = fmaxf(fmaf(p0,w0.y, fmaf(p1,w1.y, fmaf(p2,w2.y, bb.y))), 0.f);
                    float t2 = fmaxf(fmaf(p0,w0.z, fmaf(p1,w1.z, fmaf(p2,w2.z, bb.z))), 0.f);
                    float t3 = fmaxf(fmaf(p0,w0.w, fmaf(p1,w1.w, fmaf(p2,w2.w, bb.w))), 0.f);
                    ft[kt].w[2*mm+0] = pk2(t0, t1);
                    ft[kt].w[2*mm+1] = pk2(t2, t3);
                }
            f32x16 adl;
            #pragma unroll
            for (int r = 0; r < 16; r++) adl[r] = upk(pb2p, r);
            #pragma unroll
            for (int kt = 0; kt < 4; kt++)
                adl = __builtin_amdgcn_mfma_f32_32x32x16_bf16(fw_pw2[kt].v, ft[kt].v, adl, 0, 0, 0);

            // read staged fragments (aS half + xv half)
            uint2 gs2[4], gx2[4];
            #pragma unroll
            for (int g = 0; g < 4; g++) {
                int wq = q2[g] >> 1, hf = (q2[g] & 1) << 1;
                gs2[g] = *(const uint2*)&sbuf[wid][col*32 + ((wq ^ (col & 7)) << 2) + hf];
                gx2[g] = *(const uint2*)&sbuf[wid][col*32 + (((4 + wq) ^ (col & 7)) << 2) + hf];
            }

            FragU fu[2];
            #pragma unroll
            for (int kt = 0; kt < 2; kt++)
                #pragma unroll
                for (int jw = 0; jw < 4; jw++) {
                    int r0 = 8*kt + 2*jw;
                    fu[kt].w[jw] = pk2(adl[r0]   + upq(gd2, r0)   - upq(gs2, r0),
                                       adl[r0+1] + upq(gd2, r0+1) - upq(gs2, r0+1));
                }

            f32x16 ah0, ah1;
            #pragma unroll
            for (int r = 0; r < 16; r++) { ah0[r] = upk(ab1p, r); ah1[r] = upk(ab1p, 16 + r); }
            #pragma unroll
            for (int kt = 0; kt < 2; kt++) {
                ah0 = __builtin_amdgcn_mfma_f32_32x32x16_bf16(fw_aw1[0][kt].v, fu[kt].v, ah0, 0, 0, 0);
                ah1 = __builtin_amdgcn_mfma_f32_32x32x16_bf16(fw_aw1[1][kt].v, fu[kt].v, ah1, 0, 0, 0);
            }
            FragU fh[4];
            #pragma unroll
            for (int q = 0; q < 4; q++)
                #pragma unroll
                for (int jw = 0; jw < 4; jw++) {
                    int r0 = 8*(q&1) + 2*jw;
                    float x0 = (q < 2) ? ah0[r0]   : ah1[r0];
                    float x1 = (q < 2) ? ah0[r0+1] : ah1[r0+1];
                    fh[q].w[jw] = pk2(fmaxf(x0, 0.f), fmaxf(x1, 0.f));
                }
            f32x16 aa;
            #pragma unroll
            for (int r = 0; r < 16; r++) aa[r] = upk(ab2p, r);
            aa = __builtin_amdgcn_mfma_f32_32x32x16_bf16(fw_aw2[0].v, fh[0].v, aa, 0, 0, 0);
            aa = __builtin_amdgcn_mfma_f32_32x32x16_bf16(fw_aw2[1].v, fh[1].v, aa, 0, 0, 0);
            aa = __builtin_amdgcn_mfma_f32_32x32x16_bf16(fw_aw2[2].v, fh[2].v, aa, 0, 0, 0);
            aa = __builtin_amdgcn_mfma_f32_32x32x16_bf16(fw_aw2[3].v, fh[3].v, aa, 0, 0, 0);

            if (SORTED) {
                int lw = lane & 31;
                int dprev = __shfl_up(dst, 1, 32);
                bool isHead = (lw == 0) || (dprev != dst);
                bool eq1  = (__shfl_down(dst, 1, 32)  == dst) && (lw + 1  < 32);
                bool eq2  = (__shfl_down(dst, 2, 32)  == dst) && (lw + 2  < 32);
                bool eq4  = (__shfl_down(dst, 4, 32)  == dst) && (lw + 4  < 32);
                bool eq8  = (__shfl_down(dst, 8, 32)  == dst) && (lw + 8  < 32);
                bool eq16 = (__shfl_down(dst, 16, 32) == dst) && (lw + 16 < 32);
                float* drow = denom + (size_t)dst * 32;
                float* orow = outp  + (size_t)dst * 32;
                #pragma unroll
                for (int r = 0; r < 16; r++) {
                    float ea = __expf(fminf(aa[r], 35.f));
                    float ev = valid ? ea : 0.f;
                    float mv = valid ? ea * (upq(gx2, r) + adl[r]) : 0.f;
                    { float a = __shfl_down(ev,1,32),  b = __shfl_down(mv,1,32);  if (eq1)  { ev += a; mv += b; } }
                    { float a = __shfl_down(ev,2,32),  b = __shfl_down(mv,2,32);  if (eq2)  { ev += a; mv += b; } }
                    { float a = __shfl_down(ev,4,32),  b = __shfl_down(mv,4,32);  if (eq4)  { ev += a; mv += b; } }
                    { float a = __shfl_down(ev,8,32),  b = __shfl_down(mv,8,32);  if (eq8)  { ev += a; mv += b; } }
                    { float a = __shfl_down(ev,16,32), b = __shfl_down(mv,16,32); if (eq16) { ev += a; mv += b; } }
                    if (isHead) {
                        int o = 4*q2[r>>2] + (r&3);
                        unsafeAtomicAdd(drow + o, ev);
                        unsafeAtomicAdd(orow + o, mv);
                    }
                }
            } else if (valid) {
                float* drow = denom + (size_t)dst * 32;
                float* orow = outp  + (size_t)dst * 32;
                #pragma unroll
                for (int r = 0; r < 16; r++) {
                    int o = 4*q2[r>>2] + (r&3);
                    float ea = __expf(fminf(aa[r], 35.f));
                    unsafeAtomicAdd(drow + o, ea);
                    unsafeAtomicAdd(orow + o, ea * (upq(gx2, r) + adl[r]));
                }
            }
            // rotate
            c_src = n_src; c_dst = n_dst; c_ps = n_ps; c_pd = n_pd;
            c_sv0 = n_sv0; c_sv1 = n_sv1; c_sv2 = n_sv2; c_sv3 = n_sv3;
            t = tn;
        }
    } else {
        // generic fallback: per-lane scalar gathers, no staging
        for (int t = gw; t < nT; t += nW) {
            int e = t*32 + col;
            bool valid = e < eTot;
            int ec = valid ? e : eTot - 1;
            int src, dst;
            edge_sd<SORTED>(ec, ei, srcs, dsts, nE, src, dst);
            float4 pd = pos4[dst], ps = pos4[src];
            float p0 = pd.x - ps.x, p1 = pd.y - ps.y, p2 = pd.z - ps.z;
            const ushort* rs = (const ushort*)(asx + (size_t)src*32);
            const ushort* rd = (const ushort*)(aDb + (size_t)dst*16);
            float gSs[16], gDs[16], xg[16];
            #pragma unroll
            for (int r = 0; r < 16; r++) {
                gSs[r] = __uint_as_float(((uint)rs[rowv[r]]) << 16);
                gDs[r] = __uint_as_float(((uint)rd[rowv[r]]) << 16);
                xg[r]  = __uint_as_float(((uint)rs[32 + rowv[r]]) << 16);
            }
            FragU ft[4];
            #pragma unroll
            for (int kt = 0; kt < 4; kt++)
                #pragma unroll
                for (int mm = 0; mm < 2; mm++) {
                    int cb = 16*kt + 8*mm + 4*h;
                    float4 w0 = *(const float4*)(pw1f +       cb);
                    float4 w1 = *(const float4*)(pw1f + 64  + cb);
                    float4 w2 = *(const float4*)(pw1f + 128 + cb);
                    float4 bb = *(const float4*)(pb1f + cb);
                    float t0 = fmaxf(fmaf(p0,w0.x, fmaf(p1,w1.x, fmaf(p2,w2.x, bb.x))), 0.f);
                    float t1 = fmaxf(fmaf(p0,w0.y, fmaf(p1,w1.y, fmaf(p2,w2.y, bb.y))), 0.f);
                    float t2 = fmaxf(fmaf(p0,w0.z, fmaf(p1,w1.z, fmaf(p2,w2.z, bb.z))), 0.f);
                    float t3 = fmaxf(fmaf(p0,w0.w, fmaf(p1,w1.w, fmaf(p2,w2.w, bb.w))), 0.f);
                    ft[kt].w[2*mm+0] = pk2(t0, t1);
                    ft[kt].w[2*mm+1] = pk2(t2, t3);
                }
            f32x16 adl;
            #pragma unroll
            for (int r = 0; r < 16; r++) adl[r] = upk(pb2p, r);
            #pragma unroll
            for (int kt = 0; kt < 4; kt++)
                adl = __builtin_amdgcn_mfma_f32_32x32x16_bf16(fw_pw2[kt].v, ft[kt].v, adl, 0, 0, 0);
            FragU fu[2];
            #pragma unroll
            for (int kt = 0; kt < 2; kt++)
                #pragma unroll
                for (int jw = 0; jw < 4; jw++) {
                    int r0 = 8*kt + 2*jw;
                    fu[kt].w[jw] = pk2(adl[r0]   + gDs[r0]   - gSs[r0],
                                       adl[r0+1] + gDs[r0+1] - gSs[r0+1]);
                }
            f32x16 ah0, ah1;
            #pragma unroll
            for (int r = 0; r < 16; r++) { ah0[r] = upk(ab1p, r); ah1[r] = upk(ab1p, 16 + r); }
            #pragma unroll
            for (int kt = 0; kt < 2; kt++) {
                ah0 = __builtin_amdgcn_mfma_f32_32x32x16_bf16(fw_aw1[0][kt].v, fu[kt].v, ah0, 0, 0, 0);
                ah1 = __builtin_amdgcn_mfma_f32_32x32x16_bf16(fw_aw1[1][kt].v, fu[kt].v, ah1, 0, 0, 0);
            }
            FragU fh[4];
            #pragma unroll
            for (int q = 0; q < 4; q++)
                #pragma unroll
                for (int jw = 0; jw < 4; jw++) {
                    int r0 = 8*(q&1) + 2*jw;
                    float x0 = (q < 2) ? ah0[r0]   : ah1[r0];
                    float x1 = (q < 2) ? ah0[r0+1] : ah1[r0+1];
                    fh[q].w[jw] = pk2(fmaxf(x0, 0.f), fmaxf(x1, 0.f));
                }
            f32x16 aa;
            #pragma unroll
            for (int r = 0; r < 16; r++) aa[r] = upk(ab2p, r);
            aa = __builtin_amdgcn_mfma_f32_32x32x16_bf16(fw_aw2[0].v, fh[0].v, aa, 0, 0, 0);
            aa = __builtin_amdgcn_mfma_f32_32x32x16_bf16(fw_aw2[1].v, fh[1].v, aa, 0, 0, 0);
            aa = __builtin_amdgcn_mfma_f32_32x32x16_bf16(fw_aw2[2].v, fh[2].v, aa, 0, 0, 0);
            aa = __builtin_amdgcn_mfma_f32_32x32x16_bf16(fw_aw2[3].v, fh[3].v, aa, 0, 0, 0);
            if (SORTED) {
                int lw = lane & 31;
                int dprev = __shfl_up(dst, 1, 32);
                bool isHead = (lw == 0) || (dprev != dst);
                bool eq1  = (__shfl_down(dst, 1, 32)  == dst) && (lw + 1  < 32);
                bool eq2  = (__shfl_down(dst, 2, 32)  == dst) && (lw + 2  < 32);
                bool eq4  = (__shfl_down(dst, 4, 32)  == dst) && (lw + 4  < 32);
                bool eq8  = (__shfl_down(dst, 8, 32)  == dst) && (lw + 8  < 32);
                bool eq16 = (__shfl_down(dst, 16, 32) == dst) && (lw + 16 < 32);
                float* drow = denom + (size_t)dst * 32;
                float* orow = outp  + (size_t)dst * 32;
                #pragma unroll
                for (int r = 0; r < 16; r++) {
                    float ea = __expf(fminf(aa[r], 35.f));
                    float ev = valid ? ea : 0.f;
                    float mv = valid ? ea * (xg[r] + adl[r]) : 0.f;
                    { float a = __shfl_down(ev,1,32),  b = __shfl_down(mv,1,32);  if (eq1)  { ev += a; mv += b; } }
                    { float a = __shfl_down(ev,2,32),  b = __shfl_down(mv,2,32);  if (eq2)  { ev += a; mv += b; } }
                    { float a = __shfl_down(ev,4,32),  b = __shfl_down(mv,4,32);  if (eq4)  { ev += a; mv += b; } }
                    { float a = __shfl_down(ev,8,32),  b = __shfl_down(mv,8,32);  if (eq8)  { ev += a; mv += b; } }
                    { float a = __shfl_down(ev,16,32), b = __shfl_down(mv,16,32); if (eq16) { ev += a; mv += b; } }
                    if (isHead) {
                        int o = rowv[r];
                        unsafeAtomicAdd(drow + o, ev);
                        unsafeAtomicAdd(orow + o, mv);
                    }
                }
            } else if (valid) {
                float* drow = denom + (size_t)dst * 32;
                float* orow = outp  + (size_t)dst * 32;
                #pragma unroll
                for (int r = 0; r < 16; r++) {
                    int o = rowv[r];
                    float ea = __expf(fminf(aa[r], 35.f));
                    unsafeAtomicAdd(drow + o, ea);
                    unsafeAtomicAdd(orow + o, ea * (xg[r] + adl[r]));
                }
            }
        }
    }
}

// ---------- pass 3: out /= (denom + 1e-16) ----------
__global__ __launch_bounds__(256) void k_norm(
    float* __restrict__ out, const float* __restrict__ denom, int total)
{
    int i = blockIdx.x * 256 + threadIdx.x;
    if (i < total) out[i] = out[i] / (denom[i] + 1e-16f);
}

extern "C" void kernel_launch(void* const* d_in, const int* in_sizes, int n_in,
                              void* d_out, int out_size, void* d_ws, size_t ws_size,
                              hipStream_t stream)
{
    const float* x     = (const float*)d_in[0];
    const float* pos   = (const float*)d_in[1];
    const int*   ei    = (const int*)d_in[2];
    const float* w_lin = (const float*)d_in[3];
    const float* w_src = (const float*)d_in[4];
    const float* w_dst = (const float*)d_in[5];
    const float* pw1   = (const float*)d_in[6];
    const float* pb1   = (const float*)d_in[7];
    const float* pg    = (const float*)d_in[8];
    const float* pbeta = (const float*)d_in[9];
    const float* pw2   = (const float*)d_in[10];
    const float* pb2   = (const float*)d_in[11];
    const float* aw1   = (const float*)d_in[12];
    const float* ab1   = (const float*)d_in[13];
    const float* ag    = (const float*)d_in[14];
    const float* abeta = (const float*)d_in[15];
    const float* aw2   = (const float*)d_in[16];
    const float* ab2   = (const float*)d_in[17];
    float* out = (float*)d_out;

    const int nNodes = in_sizes[0] / 64;
    const int nE     = in_sizes[2] / 2;
    const int eTot   = nE + nNodes;

    const int PMBLK = 1024;
    const int DBLK  = 2048;

    const size_t nF = (size_t)nNodes * 32;
    uint*   asx   = (uint*)d_ws;                        // nNodes*32 uints (aS|xv 128B rows)
    uint*   aDb   = asx + (size_t)nNodes*32;            // nNodes*16 uints
    float*  pos4  = (float*)(aDb + (size_t)nNodes*16);  // nNodes*4
    float*  denom = pos4 + (size_t)nNodes*4;            // nF
    float*  stats = denom + nF;                         // 512
    float*  bn1   = stats + 512;
    float*  bn2   = bn1 + 128;
    float*  pw1f  = bn2 + 128;
    float*  pb1f  = pw1f + 192;
    float*  aw1f  = pb1f + 64;
    float*  ab1f  = aw1f + 2048;
    float*  partM = ab1f + 64;
    float*  partD = partM + (size_t)PMBLK*9;
    float*  fend  = partD + (size_t)DBLK*128;

    int* cnt    = (int*)fend;
    int* cur    = cnt + nNodes;
    int* blkS   = cur + nNodes;
    int* blkOff = blkS + 256;
    int* srcs   = blkOff + 256;
    int* dsts   = srcs + eTot;

    size_t need_sorted = (char*)(dsts + eTot) - (char*)d_ws;
    const bool sorted = ws_size >= need_sorted;

    const int nb = (nNodes + SCH - 1) / SCH;

    hipMemsetAsync(out,   0, nF * sizeof(float), stream);
    hipMemsetAsync(denom, 0, nF * sizeof(float), stream);

    k_node_lin<<<(nNodes + 255) / 256, 256, 0, stream>>>(
        x, w_src, w_dst, w_lin, asx, aDb, nNodes);
    k_pos4<<<(nNodes + 255) / 256, 256, 0, stream>>>(pos, (float4*)pos4, nNodes);

    k_pos_mom<<<PMBLK, 256, 0, stream>>>(ei, (const float4*)pos4, partM, nE);
    k_bn1_mom<<<1, 64, 0, stream>>>(partM, PMBLK, pw1, pb1, pg, pbeta, bn1,
                                    1.0f / (float)eTot);
    k_fold1<<<1, 256, 0, stream>>>(pw1, pb1, bn1, pw1f, pb1f);

    if (sorted) {
        hipMemsetAsync(cnt, 0, (size_t)nNodes * sizeof(int), stream);
        k_hist<<<(eTot + 255) / 256, 256, 0, stream>>>(ei, cnt, nE, eTot);
        k_scan1<<<nb, 256, 0, stream>>>(cnt, cur, blkS, nNodes);
        k_scan2<<<1, 256, 0, stream>>>(blkS, blkOff, nb);
        k_scan3<<<nb, 256, 0, stream>>>(cur, blkOff, nNodes);
        k_rank<<<(eTot + 255) / 256, 256, 0, stream>>>(ei, cur, srcs, dsts, nE, eTot);

        k_delta_stats<true><<<DBLK, 256, 0, stream>>>(
            ei, srcs, dsts, (const float4*)pos4, asx, aDb,
            pw1f, pb1f, pw2, pb2, aw1, partD, nE, eTot);
        k_red_stats<<<128, 256, 0, stream>>>(partD, stats + 128, DBLK);
        k_bn_fin<<<1, 64, 0, stream>>>(stats + 128, ag, abeta, ab1, bn2, 1.0f / (float)eTot);
        k_fold2<<<8, 256, 0, stream>>>(aw1, ab1, bn2, aw1f, ab1f);
        k_att_agg<true><<<DBLK, 256, 0, stream>>>(
            ei, srcs, dsts, (const float4*)pos4, asx, aDb,
            pw1f, pb1f, pw2, pb2, aw1f, ab1f, aw2, ab2, denom, out, nE, eTot);
    } else {
        k_delta_stats<false><<<DBLK, 256, 0, stream>>>(
            ei, nullptr, nullptr, (const float4*)pos4, asx, aDb,
            pw1f, pb1f, pw2, pb2, aw1, partD, nE, eTot);
        k_red_stats<<<128, 256, 0, stream>>>(partD, stats + 128, DBLK);
        k_bn_fin<<<1, 64, 0, stream>>>(stats + 128, ag, abeta, ab1, bn2, 1.0f / (float)eTot);
        k_fold2<<<8, 256, 0, stream>>>(aw1, ab1, bn2, aw1f, ab1f);
        k_att_agg<false><<<DBLK, 256, 0, stream>>>(
            ei, nullptr, nullptr, (const float4*)pos4, asx, aDb,
            pw1f, pb1f, pw2, pb2, aw1f, ab1f, aw2, ab2, denom, out, nE, eTot);
    }
    k_norm<<<(((int)nF) + 255) / 256, 256, 0, stream>>>(out, denom, (int)nF);
}